// Round 5
// baseline (204.751 us; speedup 1.0000x reference)
//
#include <hip/hip_runtime.h>
#include <hip/hip_bf16.h>

// LocalAttention B=4, L=2048, C=512, H=8, Dh=64 — round 11.
// vs round 10:
//  * Affine padded LDS layout everywhere ([bk][row] chunks, 1 pad chunk/row):
//    conflict-free reads AND writes, and all fragment addresses are
//    lane_base + imm -> ds_read_b128 offset:imm, zero per-tile address VALU.
//  * attn: in-block KV-split x2 — 512 thr / 8 waves; waves 0-3 do keys
//    0..1023, waves 4-7 keys 1024..2047 for the same 128 queries (own K/V
//    double-buffers). exp2-direct softmax => merge is linear (O=O0+O1,
//    l=l0+l1) via a 32KB LDS exchange at the epilogue. 4 waves/SIMD.

#define BB  4
#define LL  2048
#define CC  512
#define HH  8
#define DHH 64

typedef __attribute__((ext_vector_type(8)))  short bf16x8;   // 16 B
typedef __attribute__((ext_vector_type(4)))  short bf16x4;   // 8 B
typedef __attribute__((ext_vector_type(16))) float f32x16;   // MFMA C/D
typedef __attribute__((ext_vector_type(2)))  unsigned uint2v;
typedef __attribute__((ext_vector_type(4)))  unsigned uint4v;

using us = unsigned short;

#if __has_builtin(__builtin_amdgcn_exp2f)
#define EXP2(x) __builtin_amdgcn_exp2f(x)
#else
#define EXP2(x) __expf(0.6931471805599453f * (x))
#endif

__device__ __forceinline__ us f2bu(float x) {   // scalar fp32->bf16 (RNE)
    unsigned u = __float_as_uint(x);
    return (us)((u + 0x7FFFu + ((u >> 16) & 1u)) >> 16);
}
// HW packed fp32->bf16 (RNE), a -> low half, b -> high half
__device__ __forceinline__ unsigned pk2(float a, float b) {
    unsigned r;
    asm("v_cvt_pk_bf16_f32 %0, %1, %2" : "=v"(r) : "v"(a), "v"(b));
    return r;
}
__device__ __forceinline__ bf16x4 pk4(float a, float b, float c, float d) {
    uint2v u; u[0] = pk2(a, b); u[1] = pk2(c, d);
    return __builtin_bit_cast(bf16x4, u);
}

// ---------------------------------------------------------------------------
// transpose body: fp32 [b][c][n] -> bf16 [b][n][c] for one (b, c0, n0) tile
// ---------------------------------------------------------------------------
__device__ __forceinline__ void transpose_body(const float* __restrict__ X,
                                               us* __restrict__ Xt,
                                               int b, int c0, int n0, int t)
{
    __shared__ float T[64][65];

    const float* Xb = X + ((size_t)b * CC + c0) * LL + n0;
    #pragma unroll
    for (int i = 0; i < 4; ++i) {
        const int cl = (t >> 4) + 16 * i, nl = (t & 15) * 4;
        const float4 f = *(const float4*)(Xb + (size_t)cl * LL + nl);
        T[cl][nl + 0] = f.x; T[cl][nl + 1] = f.y;
        T[cl][nl + 2] = f.z; T[cl][nl + 3] = f.w;
    }
    __syncthreads();
    us* Ot = Xt + ((size_t)b * LL + n0) * CC + c0;
    #pragma unroll
    for (int i = 0; i < 2; ++i) {
        const int nl = (t >> 3) + 32 * i, cb = (t & 7) * 8;
        uint4v u;
        #pragma unroll
        for (int j = 0; j < 4; ++j)
            u[j] = pk2(T[cb + 2 * j][nl], T[cb + 2 * j + 1][nl]);
        *(bf16x8*)(Ot + (size_t)nl * CC + cb) = __builtin_bit_cast(bf16x8, u);
    }
}

__global__ __launch_bounds__(256) void transpose_cvt(const float* __restrict__ X,
                                                     us* __restrict__ Xt)
{
    transpose_body(X, Xt, blockIdx.z, blockIdx.y * 64, blockIdx.x * 64, threadIdx.x);
}

// fused: z = which*4 + b, which in {0:q, 1:k, 2:v}
__global__ __launch_bounds__(256) void transpose_cvt3(
    const float* __restrict__ Xq, const float* __restrict__ Xk,
    const float* __restrict__ Xv,
    us* __restrict__ X0, us* __restrict__ X1, us* __restrict__ X2)
{
    const int z = blockIdx.z, which = z >> 2, b = z & 3;
    const float* X = which == 0 ? Xq : (which == 1 ? Xk : Xv);
    us* Xt = which == 0 ? X0 : (which == 1 ? X1 : X2);
    transpose_body(X, Xt, b, blockIdx.y * 64, blockIdx.x * 64, threadIdx.x);
}

// ---------------------------------------------------------------------------
// fp32 -> bf16 for the four 512x512 weight matrices (one launch).
// ---------------------------------------------------------------------------
__global__ __launch_bounds__(256) void cvt_w4(const float* __restrict__ W0,
                                              const float* __restrict__ W1,
                                              const float* __restrict__ W2,
                                              const float* __restrict__ W3,
                                              us* __restrict__ out)
{
    const float* Ws[4] = {W0, W1, W2, W3};
    const float* W = Ws[blockIdx.y];
    us* O = out + (size_t)blockIdx.y * (CC * CC);
    const int i = (blockIdx.x * 256 + threadIdx.x) * 8;
    const float4 f0 = *(const float4*)(W + i);
    const float4 f1 = *(const float4*)(W + i + 4);
    uint4v u;
    u[0] = pk2(f0.x, f0.y); u[1] = pk2(f0.z, f0.w);
    u[2] = pk2(f1.x, f1.y); u[3] = pk2(f1.z, f1.w);
    *(bf16x8*)(O + i) = __builtin_bit_cast(bf16x8, u);
}

// ---------------------------------------------------------------------------
// GEMM core: Y[b][o][n] = sum_c W[o][c]*Xt[b][n][c] + bias[o].
// Block tile 128(M) x 128(N), BK=64, 256 thr = 4 waves in 2x2 (64x64/wave).
// LDS layout per tile: [bk 0..7][row 0..127 + 1 pad] 16B chunks, row stride
// 2064B -> conflict-free, affine fragment addresses (offset:imm folding).
// A tile 16512B, B tile 16512B; double-buffered = 66048B.
// mode 0: bf16 out, per-head position-major [b][h][n][64], (acc+bias)*scale
// mode 1: bf16 out, channel-major [b][o][n]
// mode 2: fp32 out, channel-major [b][o][n]
// ---------------------------------------------------------------------------
__device__ __forceinline__ void proj_body(const us* __restrict__ Xb,   // [n][c] for batch b
                                          const us* __restrict__ Wm,   // W rows m0..m0+127
                                          const float* __restrict__ bias,
                                          float scale, void* __restrict__ Yv,
                                          int b, int n0, int m0, int t, int mode)
{
    const int lane = t & 63, wave = t >> 6;
    const int quad2 = lane >> 5, l31 = lane & 31;
    const int wr = (wave >> 1) * 64, wc = (wave & 1) * 64;

    __shared__ __align__(16) char PS[66048];
    __shared__ float biasS[128];

    f32x16 acc[2][2];
    #pragma unroll
    for (int mi = 0; mi < 2; ++mi)
        #pragma unroll
        for (int ni = 0; ni < 2; ++ni)
            #pragma unroll
            for (int e = 0; e < 16; ++e) acc[mi][ni][e] = 0.f;

    if (t < 128) biasS[t] = bias[m0 + t];

    const int wrO = (t & 7) * 2064 + (t >> 3) * 16;        // staging write base
    const int rdA = quad2 * 2064 + (wr + l31) * 16;        // A fragment base
    const int rdB = 16512 + quad2 * 2064 + (wc + l31) * 16;// B fragment base

    // prologue: stage k-tile 0 into buffer 0
    #pragma unroll
    for (int i = 0; i < 4; ++i) {
        const int r = i * 32 + (t >> 3), bk = t & 7;
        *(bf16x8*)(PS + wrO + i * 512) =
            *(const bf16x8*)(Wm + (size_t)r * CC + bk * 8);
        *(bf16x8*)(PS + 16512 + wrO + i * 512) =
            *(const bf16x8*)(Xb + (size_t)(n0 + r) * CC + bk * 8);
    }
    __syncthreads();

    for (int it = 0; it < CC / 64; ++it) {
        const int cur = it & 1, k1 = (it + 1) * 64;
        char* PB = PS + (cur ? 33024 : 0);
        char* PN = PS + (cur ? 0 : 33024);

        bf16x8 apre[4], bpre[4];
        if (it + 1 < CC / 64) {
            #pragma unroll
            for (int i = 0; i < 4; ++i) {
                const int r = i * 32 + (t >> 3), bk = t & 7;
                apre[i] = *(const bf16x8*)(Wm + (size_t)r * CC + k1 + bk * 8);
                bpre[i] = *(const bf16x8*)(Xb + (size_t)(n0 + r) * CC + k1 + bk * 8);
            }
        }

        __builtin_amdgcn_s_setprio(1);
        #pragma unroll
        for (int ks = 0; ks < 4; ++ks) {
            const bf16x8 af0 = *(const bf16x8*)(PB + rdA + ks * 4128);
            const bf16x8 af1 = *(const bf16x8*)(PB + rdA + ks * 4128 + 512);
            const bf16x8 bf0 = *(const bf16x8*)(PB + rdB + ks * 4128);
            const bf16x8 bf1 = *(const bf16x8*)(PB + rdB + ks * 4128 + 512);
            acc[0][0] = __builtin_amdgcn_mfma_f32_32x32x16_bf16(af0, bf0, acc[0][0], 0, 0, 0);
            acc[0][1] = __builtin_amdgcn_mfma_f32_32x32x16_bf16(af0, bf1, acc[0][1], 0, 0, 0);
            acc[1][0] = __builtin_amdgcn_mfma_f32_32x32x16_bf16(af1, bf0, acc[1][0], 0, 0, 0);
            acc[1][1] = __builtin_amdgcn_mfma_f32_32x32x16_bf16(af1, bf1, acc[1][1], 0, 0, 0);
        }
        __builtin_amdgcn_s_setprio(0);

        if (it + 1 < CC / 64) {
            #pragma unroll
            for (int i = 0; i < 4; ++i) {
                *(bf16x8*)(PN + wrO + i * 512) = apre[i];
                *(bf16x8*)(PN + 16512 + wrO + i * 512) = bpre[i];
            }
        }
        __syncthreads();
    }

    #pragma unroll
    for (int mi = 0; mi < 2; ++mi)
        #pragma unroll
        for (int ni = 0; ni < 2; ++ni) {
            const int nloc = wc + ni * 32 + l31;
            if (mode == 0) {
                us* Y = (us*)Yv;
                #pragma unroll
                for (int rg2 = 0; rg2 < 4; ++rg2) {
                    const int rbase = wr + mi * 32 + 8 * rg2 + 4 * quad2;
                    float v0 = (acc[mi][ni][rg2 * 4 + 0] + biasS[rbase + 0]) * scale;
                    float v1 = (acc[mi][ni][rg2 * 4 + 1] + biasS[rbase + 1]) * scale;
                    float v2 = (acc[mi][ni][rg2 * 4 + 2] + biasS[rbase + 2]) * scale;
                    float v3 = (acc[mi][ni][rg2 * 4 + 3] + biasS[rbase + 3]) * scale;
                    const int mg = m0 + rbase;
                    const int h = mg >> 6, d = mg & 63;
                    *(bf16x4*)(Y + (((size_t)(b * HH + h) * LL) + n0 + nloc) * DHH + d) =
                        pk4(v0, v1, v2, v3);
                }
            } else {
                #pragma unroll
                for (int reg = 0; reg < 16; ++reg) {
                    const int row = (reg & 3) + 8 * (reg >> 2) + 4 * quad2;
                    const int mloc = wr + mi * 32 + row;
                    const float v = (acc[mi][ni][reg] + biasS[mloc]) * scale;
                    const size_t addr = ((size_t)b * CC + m0 + mloc) * LL + n0 + nloc;
                    if (mode == 1) ((us*)Yv)[addr] = f2bu(v);
                    else           ((float*)Yv)[addr] = v;
                }
            }
        }
}

template <int MODE>
__global__ __launch_bounds__(256, 2) void proj_gemm(const us* __restrict__ Xt,
                                                    const us* __restrict__ Wb,
                                                    const float* __restrict__ bias,
                                                    float scale,
                                                    void* __restrict__ Yv)
{
    const int b = blockIdx.z, n0 = blockIdx.x * 128, m0 = blockIdx.y * 128;
    proj_body(Xt + (size_t)b * LL * CC, Wb + (size_t)m0 * CC, bias, scale, Yv,
              b, n0, m0, threadIdx.x, MODE);
}

// fused q/k/v projection: z = which*4 + b
__global__ __launch_bounds__(256, 2) void proj_gemm3(
    const us* __restrict__ X0, const us* __restrict__ X1, const us* __restrict__ X2,
    const us* __restrict__ Wb4,
    const float* __restrict__ bq, const float* __restrict__ bk,
    const float* __restrict__ bv, float scale_q,
    us* __restrict__ qh, us* __restrict__ kh, us* __restrict__ vh)
{
    const int z = blockIdx.z, which = z >> 2, b = z & 3;
    const int n0 = blockIdx.x * 128, m0 = blockIdx.y * 128;
    const us* Xt = which == 0 ? X0 : (which == 1 ? X1 : X2);
    const us* Wb = Wb4 + (size_t)which * (CC * CC);
    const float* bias = which == 0 ? bq : (which == 1 ? bk : bv);
    const float scale = which == 0 ? scale_q : 1.0f;
    us* Yv = which == 0 ? qh : (which == 1 ? kh : vh);
    const int mode = (which == 2) ? 1 : 0;
    proj_body(Xt + (size_t)b * LL * CC, Wb + (size_t)m0 * CC, bias, scale,
              (void*)Yv, b, n0, m0, threadIdx.x, mode);
}

// ---------------------------------------------------------------------------
// Flash attention, in-block KV-split x2. 512 thr = 8 waves; half = wave>>2.
// Waves 0-3 process keys 0..1023, waves 4-7 keys 1024..2047 for the SAME
// 128 queries (each of 4 query groups handled by one wave per half).
// Per half: own K/V double-buffer in the affine padded layout
// ([bk][row]+pad, row stride 1040B) -> conflict-free, offset:imm reads.
// exp2-direct softmax (q pre-scaled by 0.125*log2e) => halves merge
// linearly at the epilogue through a 32KB LDS exchange: O=O0+O1, l=l0+l1.
// P stays in registers (cvt_pk + permlane32_swap -> PV B-fragments).
// ---------------------------------------------------------------------------
__global__ __launch_bounds__(512, 4) void attn_fwd(
    const us* __restrict__ Qh,     // [b][h][l][64], pre-scaled
    const us* __restrict__ Kh,     // [b][h][l][64]
    const us* __restrict__ Vh,     // [b][512][l] channel-major
    const float* __restrict__ mask,// [b][1][L]
    us* __restrict__ ctx)          // [b][l][512]
{
    const int bh = blockIdx.x;     // 0..31
    const int b = bh >> 3, h = bh & 7;
    const int qb = blockIdx.y;     // 0..15
    const int t = threadIdx.x, lane = t & 63, wave = t >> 6;
    const int half = wave >> 2, wv = wave & 3;
    const int quad2 = lane >> 5, l31 = lane & 31;
    const int th = t & 255;
    const int qg = qb * 128 + wv * 32;       // wave's query base

    __shared__ __align__(16) char SM[66560]; // 2 halves x 2 bufs x (K 8320 + V 8320)
    __shared__ unsigned long long mwS[32];

    const float* mb = mask + (size_t)b * LL;
    #pragma unroll
    for (int i = 0; i < 4; ++i) {            // 8 waves x 4 = all 32 ballots
        const int tile = wave * 4 + i;
        const unsigned long long bal = __ballot(mb[tile * 64 + lane] > 0.5f);
        if (lane == 0) mwS[tile] = bal;
    }

    // Q fragments (register-resident); both halves load the same queries
    const us* Qbase = Qh + (size_t)bh * LL * DHH;
    bf16x8 qf[4];
    #pragma unroll
    for (int ks = 0; ks < 4; ++ks)
        qf[ks] = *(const bf16x8*)(Qbase + (size_t)(qg + l31) * DHH + ks * 16 + quad2 * 8);

    f32x16 of[2];
    #pragma unroll
    for (int mt = 0; mt < 2; ++mt)
        #pragma unroll
        for (int e = 0; e < 16; ++e) of[mt][e] = 0.f;
    float l_run = 0.f;

    const us* Kbase = Kh + (size_t)bh * LL * DHH;
    const us* Vbase = Vh + ((size_t)b * CC + h * DHH) * LL;

    char* SH = SM + half * 33280;            // this half's staging region
    const int wrO = (th & 7) * 1040 + (th >> 3) * 16;  // staging write base
    const int rdO = quad2 * 1040 + l31 * 16;           // fragment read base
    const int g0 = half * 16;                // first tile of this half

    // stage tile g0 into buffer 0
    #pragma unroll
    for (int i = 0; i < 2; ++i) {
        const int r = i * 32 + (th >> 3), bk = th & 7;
        *(bf16x8*)(SH + wrO + i * 512) =
            *(const bf16x8*)(Kbase + (size_t)(g0 * 64 + r) * DHH + bk * 8);
        *(bf16x8*)(SH + 8320 + wrO + i * 512) =
            *(const bf16x8*)(Vbase + (size_t)r * LL + g0 * 64 + bk * 8);
    }
    __syncthreads();

    // QK^T for local tile 0
    f32x16 sf[2];
    #pragma unroll
    for (int mt = 0; mt < 2; ++mt)
        #pragma unroll
        for (int e = 0; e < 16; ++e) sf[mt][e] = 0.f;
    {
        const char* pK = SH + rdO;
        __builtin_amdgcn_s_setprio(1);
        #pragma unroll
        for (int ks = 0; ks < 4; ++ks)
            #pragma unroll
            for (int mt = 0; mt < 2; ++mt)
                sf[mt] = __builtin_amdgcn_mfma_f32_32x32x16_bf16(
                    *(const bf16x8*)(pK + ks * 2080 + mt * 512), qf[ks], sf[mt], 0, 0, 0);
        __builtin_amdgcn_s_setprio(0);
    }

    for (int itl = 0; itl < 16; ++itl) {
        const int cur = itl & 1;
        char* SB = SH + (cur ? 16640 : 0);   // buffer holding tile itl
        char* SN = SH + (cur ? 0 : 16640);   // buffer for tile itl+1

        // prefetch next K/V tile into registers (issue early)
        bf16x8 kpre[2], vpre[2];
        if (itl + 1 < 16) {
            const int n1 = (g0 + itl + 1) * 64;
            #pragma unroll
            for (int i = 0; i < 2; ++i) {
                const int r = i * 32 + (th >> 3), bk = th & 7;
                kpre[i] = *(const bf16x8*)(Kbase + (size_t)(n1 + r) * DHH + bk * 8);
                vpre[i] = *(const bf16x8*)(Vbase + (size_t)r * LL + n1 + bk * 8);
            }
        }

        // exp2-direct softmax on sf (tile g0+itl)
        const unsigned long long mw = mwS[g0 + itl];
        const bool masked = (mw != 0xFFFFFFFFFFFFFFFFull);
        float ps = 0.f;
        bf16x8 pfrag[4];
        #pragma unroll
        for (int mt = 0; mt < 2; ++mt) {
            float p[16];
            #pragma unroll
            for (int e = 0; e < 16; ++e) p[e] = EXP2(sf[mt][e]);
            if (masked) {
                #pragma unroll
                for (int e = 0; e < 16; ++e) {
                    const int row = 32 * mt + (e & 3) + 8 * (e >> 2) + 4 * quad2;
                    p[e] = ((mw >> row) & 1ull) ? p[e] : 0.f;
                }
            }
            const float s0 = (p[0] + p[1]) + (p[2] + p[3]);
            const float s1 = (p[4] + p[5]) + (p[6] + p[7]);
            const float s2 = (p[8] + p[9]) + (p[10] + p[11]);
            const float s3 = (p[12] + p[13]) + (p[14] + p[15]);
            ps += (s0 + s1) + (s2 + s3);
            // v_permlane32_swap_b32 vdst, vsrc:
            //   new_vdst = {lo: old_vdst.lo, hi: old_vsrc.lo}
            //   new_vsrc = {lo: old_vdst.hi, hi: old_vsrc.hi}
            // => vdst = low-n pair word (w0/w1), vsrc = +4 pair word (w2/w3).
            #pragma unroll
            for (int g = 0; g < 2; ++g) {
                unsigned w0 = pk2(p[8 * g + 0], p[8 * g + 1]);
                unsigned w1 = pk2(p[8 * g + 2], p[8 * g + 3]);
                unsigned w2 = pk2(p[8 * g + 4], p[8 * g + 5]);
                unsigned w3 = pk2(p[8 * g + 6], p[8 * g + 7]);
                asm("v_permlane32_swap_b32 %0, %1" : "+v"(w0), "+v"(w2));
                asm("v_permlane32_swap_b32 %0, %1" : "+v"(w1), "+v"(w3));
                uint4v u; u[0] = w0; u[1] = w1; u[2] = w2; u[3] = w3;
                pfrag[2 * mt + g] = __builtin_bit_cast(bf16x8, u);
            }
        }
        ps += __shfl_xor(ps, 32, 64);
        l_run += ps;

        // O^T += V P^T (tile g0+itl)
        __builtin_amdgcn_s_setprio(1);
        #pragma unroll
        for (int ks = 0; ks < 4; ++ks)
            #pragma unroll
            for (int mt = 0; mt < 2; ++mt) {
                const bf16x8 vf = *(const bf16x8*)(SB + 8320 + rdO + ks * 2080 + mt * 512);
                of[mt] = __builtin_amdgcn_mfma_f32_32x32x16_bf16(vf, pfrag[ks], of[mt], 0, 0, 0);
            }
        __builtin_amdgcn_s_setprio(0);

        // write prefetched tile itl+1 to the alternate buffer
        if (itl + 1 < 16) {
            #pragma unroll
            for (int i = 0; i < 2; ++i) {
                *(bf16x8*)(SN + wrO + i * 512) = kpre[i];
                *(bf16x8*)(SN + 8320 + wrO + i * 512) = vpre[i];
            }
        }
        __syncthreads();

        // QK^T for tile itl+1 (pipelined: consumed next iteration)
        if (itl + 1 < 16) {
            #pragma unroll
            for (int mt = 0; mt < 2; ++mt)
                #pragma unroll
                for (int e = 0; e < 16; ++e) sf[mt][e] = 0.f;
            __builtin_amdgcn_s_setprio(1);
            #pragma unroll
            for (int ks = 0; ks < 4; ++ks)
                #pragma unroll
                for (int mt = 0; mt < 2; ++mt)
                    sf[mt] = __builtin_amdgcn_mfma_f32_32x32x16_bf16(
                        *(const bf16x8*)(SN + rdO + ks * 2080 + mt * 512), qf[ks], sf[mt], 0, 0, 0);
            __builtin_amdgcn_s_setprio(0);
        }
    }

    // epilogue: merge halves (O = O0+O1, l = l0+l1), then ctx = O/l.
    // half1 parks its partials in LDS ([e4-chunk][lane] float4 layout,
    // 16B lane stride -> conflict-free); half0 combines and writes.
    float4* OS = (float4*)SM;                // 4 wv x 8 e4 x 64 lanes = 32KB
    float*  LS = (float*)(SM + 32768);       // 4 wv x 64 lanes
    if (half == 1) {
        #pragma unroll
        for (int mt = 0; mt < 2; ++mt)
            #pragma unroll
            for (int r4 = 0; r4 < 4; ++r4) {
                float4 v;
                v.x = of[mt][r4 * 4 + 0]; v.y = of[mt][r4 * 4 + 1];
                v.z = of[mt][r4 * 4 + 2]; v.w = of[mt][r4 * 4 + 3];
                OS[(wv * 8 + mt * 4 + r4) * 64 + lane] = v;
            }
        LS[wv * 64 + lane] = l_run;
    }
    __syncthreads();
    if (half == 0) {
        l_run += LS[wv * 64 + lane];
        const float inv = 1.0f / l_run;
        us* Cb = ctx + (size_t)b * LL * CC;
        const int q = qg + l31;
        #pragma unroll
        for (int mt = 0; mt < 2; ++mt)
            #pragma unroll
            for (int r4 = 0; r4 < 4; ++r4) {
                const float4 v = OS[(wv * 8 + mt * 4 + r4) * 64 + lane];
                const int d = 32 * mt + 8 * r4 + 4 * quad2;
                *(bf16x4*)(Cb + (size_t)q * CC + h * DHH + d) =
                    pk4((of[mt][r4 * 4 + 0] + v.x) * inv,
                        (of[mt][r4 * 4 + 1] + v.y) * inv,
                        (of[mt][r4 * 4 + 2] + v.z) * inv,
                        (of[mt][r4 * 4 + 3] + v.w) * inv);
            }
    }
}

// ---------------------------------------------------------------------------
extern "C" void kernel_launch(void* const* d_in, const int* in_sizes, int n_in,
                              void* d_out, int out_size, void* d_ws, size_t ws_size,
                              hipStream_t stream)
{
    const float* q    = (const float*)d_in[0];
    const float* k    = (const float*)d_in[1];
    const float* v    = (const float*)d_in[2];
    const float* mask = (const float*)d_in[3];
    const float* Wq   = (const float*)d_in[4];
    const float* bq   = (const float*)d_in[5];
    const float* Wk   = (const float*)d_in[6];
    const float* bk   = (const float*)d_in[7];
    const float* Wv   = (const float*)d_in[8];
    const float* bv   = (const float*)d_in[9];
    const float* Wout = (const float*)d_in[10];
    const float* bout = (const float*)d_in[11];

    const size_t TSZ  = (size_t)BB * CC * LL;    // 4,194,304 elements (8 MB)
    const size_t WSZ  = (size_t)4 * CC * CC;     // 1,048,576 elements (2 MB)
    const float SCALE_Q = 0.125f * 1.4426950408889634f;  // softmax scale * log2e

    const dim3 tb(256), gb(256);

    if (ws_size >= (6 * TSZ + WSZ) * sizeof(us)) {
        // fused path: 5 launches
        us* X0  = (us*)d_ws;
        us* X1  = X0 + TSZ;
        us* X2  = X1 + TSZ;
        us* qh  = X2 + TSZ;
        us* kh  = qh + TSZ;
        us* vh  = kh + TSZ;
        us* Wb  = vh + TSZ;
        us* ctx = X0;                            // X0 dead after proj3

        cvt_w4<<<dim3(CC * CC / 2048, 4), tb, 0, stream>>>(Wq, Wk, Wv, Wout, Wb);
        transpose_cvt3<<<dim3(LL / 64, CC / 64, 12), tb, 0, stream>>>(q, k, v, X0, X1, X2);
        proj_gemm3<<<dim3(LL / 128, CC / 128, 12), gb, 0, stream>>>(
            X0, X1, X2, Wb, bq, bk, bv, SCALE_Q, qh, kh, vh);
        attn_fwd<<<dim3(HH * BB, LL / 128), dim3(512), 0, stream>>>(qh, kh, vh, mask, ctx);
        proj_gemm<2><<<dim3(LL / 128, CC / 128, BB), gb, 0, stream>>>(
            ctx, Wb + 3 * (size_t)CC * CC, bout, 1.0f, d_out);
    } else {
        // fallback: sequential path reusing one Xt buffer
        us* Xt  = (us*)d_ws;
        us* qh  = Xt + TSZ;
        us* kh  = qh + TSZ;
        us* vh  = kh + TSZ;
        us* Wb  = vh + TSZ;
        us* ctx = Xt;

        const dim3 tg(LL / 64, CC / 64, BB), gg(LL / 128, CC / 128, BB);

        cvt_w4<<<dim3(CC * CC / 2048, 4), tb, 0, stream>>>(Wq, Wk, Wv, Wout, Wb);
        transpose_cvt<<<tg, tb, 0, stream>>>(q, Xt);
        proj_gemm<0><<<gg, gb, 0, stream>>>(Xt, Wb + 0 * (size_t)CC * CC, bq, SCALE_Q, (void*)qh);
        transpose_cvt<<<tg, tb, 0, stream>>>(k, Xt);
        proj_gemm<0><<<gg, gb, 0, stream>>>(Xt, Wb + 1 * (size_t)CC * CC, bk, 1.0f, (void*)kh);
        transpose_cvt<<<tg, tb, 0, stream>>>(v, Xt);
        proj_gemm<1><<<gg, gb, 0, stream>>>(Xt, Wb + 2 * (size_t)CC * CC, bv, 1.0f, (void*)vh);
        attn_fwd<<<dim3(HH * BB, LL / 128), dim3(512), 0, stream>>>(qh, kh, vh, mask, ctx);
        proj_gemm<2><<<gg, gb, 0, stream>>>(ctx, Wb + 3 * (size_t)CC * CC, bout, 1.0f, d_out);
    }
}

// Round 6
// 192.874 us; speedup vs baseline: 1.0616x; 1.0616x over previous
//
#include <hip/hip_runtime.h>
#include <hip/hip_bf16.h>

// LocalAttention B=4, L=2048, C=512, H=8, Dh=64 — round 12.
// vs round 11: attn KV-split kept but register-budgeted to fit 128/thread
// (4 waves/SIMD, no spill): Q staged to LDS (shared by halves, affine reads),
// no cross-tile QK pipeline, V single-buffered (2 barriers/tile).
// LDS 66.6KB/block -> 2 blocks/CU. Affine padded K/V layout (round-11,
// bank-conflicts measured 0). proj/transpose unchanged from round 11.

#define BB  4
#define LL  2048
#define CC  512
#define HH  8
#define DHH 64

typedef __attribute__((ext_vector_type(8)))  short bf16x8;   // 16 B
typedef __attribute__((ext_vector_type(4)))  short bf16x4;   // 8 B
typedef __attribute__((ext_vector_type(16))) float f32x16;   // MFMA C/D
typedef __attribute__((ext_vector_type(2)))  unsigned uint2v;
typedef __attribute__((ext_vector_type(4)))  unsigned uint4v;

using us = unsigned short;

#if __has_builtin(__builtin_amdgcn_exp2f)
#define EXP2(x) __builtin_amdgcn_exp2f(x)
#else
#define EXP2(x) __expf(0.6931471805599453f * (x))
#endif

__device__ __forceinline__ us f2bu(float x) {   // scalar fp32->bf16 (RNE)
    unsigned u = __float_as_uint(x);
    return (us)((u + 0x7FFFu + ((u >> 16) & 1u)) >> 16);
}
// HW packed fp32->bf16 (RNE), a -> low half, b -> high half
__device__ __forceinline__ unsigned pk2(float a, float b) {
    unsigned r;
    asm("v_cvt_pk_bf16_f32 %0, %1, %2" : "=v"(r) : "v"(a), "v"(b));
    return r;
}
__device__ __forceinline__ bf16x4 pk4(float a, float b, float c, float d) {
    uint2v u; u[0] = pk2(a, b); u[1] = pk2(c, d);
    return __builtin_bit_cast(bf16x4, u);
}

// ---------------------------------------------------------------------------
// transpose body: fp32 [b][c][n] -> bf16 [b][n][c] for one (b, c0, n0) tile
// ---------------------------------------------------------------------------
__device__ __forceinline__ void transpose_body(const float* __restrict__ X,
                                               us* __restrict__ Xt,
                                               int b, int c0, int n0, int t)
{
    __shared__ float T[64][65];

    const float* Xb = X + ((size_t)b * CC + c0) * LL + n0;
    #pragma unroll
    for (int i = 0; i < 4; ++i) {
        const int cl = (t >> 4) + 16 * i, nl = (t & 15) * 4;
        const float4 f = *(const float4*)(Xb + (size_t)cl * LL + nl);
        T[cl][nl + 0] = f.x; T[cl][nl + 1] = f.y;
        T[cl][nl + 2] = f.z; T[cl][nl + 3] = f.w;
    }
    __syncthreads();
    us* Ot = Xt + ((size_t)b * LL + n0) * CC + c0;
    #pragma unroll
    for (int i = 0; i < 2; ++i) {
        const int nl = (t >> 3) + 32 * i, cb = (t & 7) * 8;
        uint4v u;
        #pragma unroll
        for (int j = 0; j < 4; ++j)
            u[j] = pk2(T[cb + 2 * j][nl], T[cb + 2 * j + 1][nl]);
        *(bf16x8*)(Ot + (size_t)nl * CC + cb) = __builtin_bit_cast(bf16x8, u);
    }
}

__global__ __launch_bounds__(256) void transpose_cvt(const float* __restrict__ X,
                                                     us* __restrict__ Xt)
{
    transpose_body(X, Xt, blockIdx.z, blockIdx.y * 64, blockIdx.x * 64, threadIdx.x);
}

// fused: z = which*4 + b, which in {0:q, 1:k, 2:v}
__global__ __launch_bounds__(256) void transpose_cvt3(
    const float* __restrict__ Xq, const float* __restrict__ Xk,
    const float* __restrict__ Xv,
    us* __restrict__ X0, us* __restrict__ X1, us* __restrict__ X2)
{
    const int z = blockIdx.z, which = z >> 2, b = z & 3;
    const float* X = which == 0 ? Xq : (which == 1 ? Xk : Xv);
    us* Xt = which == 0 ? X0 : (which == 1 ? X1 : X2);
    transpose_body(X, Xt, b, blockIdx.y * 64, blockIdx.x * 64, threadIdx.x);
}

// ---------------------------------------------------------------------------
// fp32 -> bf16 for the four 512x512 weight matrices (one launch).
// ---------------------------------------------------------------------------
__global__ __launch_bounds__(256) void cvt_w4(const float* __restrict__ W0,
                                              const float* __restrict__ W1,
                                              const float* __restrict__ W2,
                                              const float* __restrict__ W3,
                                              us* __restrict__ out)
{
    const float* Ws[4] = {W0, W1, W2, W3};
    const float* W = Ws[blockIdx.y];
    us* O = out + (size_t)blockIdx.y * (CC * CC);
    const int i = (blockIdx.x * 256 + threadIdx.x) * 8;
    const float4 f0 = *(const float4*)(W + i);
    const float4 f1 = *(const float4*)(W + i + 4);
    uint4v u;
    u[0] = pk2(f0.x, f0.y); u[1] = pk2(f0.z, f0.w);
    u[2] = pk2(f1.x, f1.y); u[3] = pk2(f1.z, f1.w);
    *(bf16x8*)(O + i) = __builtin_bit_cast(bf16x8, u);
}

// ---------------------------------------------------------------------------
// GEMM core: Y[b][o][n] = sum_c W[o][c]*Xt[b][n][c] + bias[o].
// Block tile 128(M) x 128(N), BK=64, 256 thr = 4 waves in 2x2 (64x64/wave).
// LDS layout per tile: [bk 0..7][row 0..127 + 1 pad] 16B chunks, row stride
// 2064B -> conflict-free, affine fragment addresses (offset:imm folding).
// mode 0: bf16 out, per-head position-major [b][h][n][64], (acc+bias)*scale
// mode 1: bf16 out, channel-major [b][o][n]
// mode 2: fp32 out, channel-major [b][o][n]
// ---------------------------------------------------------------------------
__device__ __forceinline__ void proj_body(const us* __restrict__ Xb,   // [n][c] for batch b
                                          const us* __restrict__ Wm,   // W rows m0..m0+127
                                          const float* __restrict__ bias,
                                          float scale, void* __restrict__ Yv,
                                          int b, int n0, int m0, int t, int mode)
{
    const int lane = t & 63, wave = t >> 6;
    const int quad2 = lane >> 5, l31 = lane & 31;
    const int wr = (wave >> 1) * 64, wc = (wave & 1) * 64;

    __shared__ __align__(16) char PS[66048];
    __shared__ float biasS[128];

    f32x16 acc[2][2];
    #pragma unroll
    for (int mi = 0; mi < 2; ++mi)
        #pragma unroll
        for (int ni = 0; ni < 2; ++ni)
            #pragma unroll
            for (int e = 0; e < 16; ++e) acc[mi][ni][e] = 0.f;

    if (t < 128) biasS[t] = bias[m0 + t];

    const int wrO = (t & 7) * 2064 + (t >> 3) * 16;        // staging write base
    const int rdA = quad2 * 2064 + (wr + l31) * 16;        // A fragment base
    const int rdB = 16512 + quad2 * 2064 + (wc + l31) * 16;// B fragment base

    // prologue: stage k-tile 0 into buffer 0
    #pragma unroll
    for (int i = 0; i < 4; ++i) {
        const int r = i * 32 + (t >> 3), bk = t & 7;
        *(bf16x8*)(PS + wrO + i * 512) =
            *(const bf16x8*)(Wm + (size_t)r * CC + bk * 8);
        *(bf16x8*)(PS + 16512 + wrO + i * 512) =
            *(const bf16x8*)(Xb + (size_t)(n0 + r) * CC + bk * 8);
    }
    __syncthreads();

    for (int it = 0; it < CC / 64; ++it) {
        const int cur = it & 1, k1 = (it + 1) * 64;
        char* PB = PS + (cur ? 33024 : 0);
        char* PN = PS + (cur ? 0 : 33024);

        bf16x8 apre[4], bpre[4];
        if (it + 1 < CC / 64) {
            #pragma unroll
            for (int i = 0; i < 4; ++i) {
                const int r = i * 32 + (t >> 3), bk = t & 7;
                apre[i] = *(const bf16x8*)(Wm + (size_t)r * CC + k1 + bk * 8);
                bpre[i] = *(const bf16x8*)(Xb + (size_t)(n0 + r) * CC + k1 + bk * 8);
            }
        }

        __builtin_amdgcn_s_setprio(1);
        #pragma unroll
        for (int ks = 0; ks < 4; ++ks) {
            const bf16x8 af0 = *(const bf16x8*)(PB + rdA + ks * 4128);
            const bf16x8 af1 = *(const bf16x8*)(PB + rdA + ks * 4128 + 512);
            const bf16x8 bf0 = *(const bf16x8*)(PB + rdB + ks * 4128);
            const bf16x8 bf1 = *(const bf16x8*)(PB + rdB + ks * 4128 + 512);
            acc[0][0] = __builtin_amdgcn_mfma_f32_32x32x16_bf16(af0, bf0, acc[0][0], 0, 0, 0);
            acc[0][1] = __builtin_amdgcn_mfma_f32_32x32x16_bf16(af0, bf1, acc[0][1], 0, 0, 0);
            acc[1][0] = __builtin_amdgcn_mfma_f32_32x32x16_bf16(af1, bf0, acc[1][0], 0, 0, 0);
            acc[1][1] = __builtin_amdgcn_mfma_f32_32x32x16_bf16(af1, bf1, acc[1][1], 0, 0, 0);
        }
        __builtin_amdgcn_s_setprio(0);

        if (it + 1 < CC / 64) {
            #pragma unroll
            for (int i = 0; i < 4; ++i) {
                *(bf16x8*)(PN + wrO + i * 512) = apre[i];
                *(bf16x8*)(PN + 16512 + wrO + i * 512) = bpre[i];
            }
        }
        __syncthreads();
    }

    #pragma unroll
    for (int mi = 0; mi < 2; ++mi)
        #pragma unroll
        for (int ni = 0; ni < 2; ++ni) {
            const int nloc = wc + ni * 32 + l31;
            if (mode == 0) {
                us* Y = (us*)Yv;
                #pragma unroll
                for (int rg2 = 0; rg2 < 4; ++rg2) {
                    const int rbase = wr + mi * 32 + 8 * rg2 + 4 * quad2;
                    float v0 = (acc[mi][ni][rg2 * 4 + 0] + biasS[rbase + 0]) * scale;
                    float v1 = (acc[mi][ni][rg2 * 4 + 1] + biasS[rbase + 1]) * scale;
                    float v2 = (acc[mi][ni][rg2 * 4 + 2] + biasS[rbase + 2]) * scale;
                    float v3 = (acc[mi][ni][rg2 * 4 + 3] + biasS[rbase + 3]) * scale;
                    const int mg = m0 + rbase;
                    const int h = mg >> 6, d = mg & 63;
                    *(bf16x4*)(Y + (((size_t)(b * HH + h) * LL) + n0 + nloc) * DHH + d) =
                        pk4(v0, v1, v2, v3);
                }
            } else {
                #pragma unroll
                for (int reg = 0; reg < 16; ++reg) {
                    const int row = (reg & 3) + 8 * (reg >> 2) + 4 * quad2;
                    const int mloc = wr + mi * 32 + row;
                    const float v = (acc[mi][ni][reg] + biasS[mloc]) * scale;
                    const size_t addr = ((size_t)b * CC + m0 + mloc) * LL + n0 + nloc;
                    if (mode == 1) ((us*)Yv)[addr] = f2bu(v);
                    else           ((float*)Yv)[addr] = v;
                }
            }
        }
}

template <int MODE>
__global__ __launch_bounds__(256, 2) void proj_gemm(const us* __restrict__ Xt,
                                                    const us* __restrict__ Wb,
                                                    const float* __restrict__ bias,
                                                    float scale,
                                                    void* __restrict__ Yv)
{
    const int b = blockIdx.z, n0 = blockIdx.x * 128, m0 = blockIdx.y * 128;
    proj_body(Xt + (size_t)b * LL * CC, Wb + (size_t)m0 * CC, bias, scale, Yv,
              b, n0, m0, threadIdx.x, MODE);
}

// fused q/k/v projection: z = which*4 + b
__global__ __launch_bounds__(256, 2) void proj_gemm3(
    const us* __restrict__ X0, const us* __restrict__ X1, const us* __restrict__ X2,
    const us* __restrict__ Wb4,
    const float* __restrict__ bq, const float* __restrict__ bk,
    const float* __restrict__ bv, float scale_q,
    us* __restrict__ qh, us* __restrict__ kh, us* __restrict__ vh)
{
    const int z = blockIdx.z, which = z >> 2, b = z & 3;
    const int n0 = blockIdx.x * 128, m0 = blockIdx.y * 128;
    const us* Xt = which == 0 ? X0 : (which == 1 ? X1 : X2);
    const us* Wb = Wb4 + (size_t)which * (CC * CC);
    const float* bias = which == 0 ? bq : (which == 1 ? bk : bv);
    const float scale = which == 0 ? scale_q : 1.0f;
    us* Yv = which == 0 ? qh : (which == 1 ? kh : vh);
    const int mode = (which == 2) ? 1 : 0;
    proj_body(Xt + (size_t)b * LL * CC, Wb + (size_t)m0 * CC, bias, scale,
              (void*)Yv, b, n0, m0, threadIdx.x, mode);
}

// ---------------------------------------------------------------------------
// Flash attention, in-block KV-split x2, register-budgeted for 4 waves/SIMD.
// 512 thr = 8 waves; half = wave>>2. Waves 0-3: keys 0..1023, waves 4-7:
// keys 1024..2047, same 128 queries. Q staged ONCE to LDS [bk][row] (16KB,
// shared by halves) and re-read per tile (affine offset:imm). Per half:
// K double-buffered, V single-buffered (2 barriers/tile), padded affine
// layout (row stride 1040B, conflict-free, measured 0 conflicts).
// exp2-direct softmax (q pre-scaled 0.125*log2e); halves merge linearly at
// the epilogue via a 32KB LDS exchange (O=O0+O1, l=l0+l1).
// P stays in registers (cvt_pk + permlane32_swap -> PV B-fragments).
// LDS: Q 16384 | K 2x2x8320 | V 2x8320 | ballots 256 = 66560 B.
// ---------------------------------------------------------------------------
__global__ __launch_bounds__(512, 4) void attn_fwd(
    const us* __restrict__ Qh,     // [b][h][l][64], pre-scaled
    const us* __restrict__ Kh,     // [b][h][l][64]
    const us* __restrict__ Vh,     // [b][512][l] channel-major
    const float* __restrict__ mask,// [b][1][L]
    us* __restrict__ ctx)          // [b][l][512]
{
    const int bh = blockIdx.x;     // 0..31
    const int b = bh >> 3, h = bh & 7;
    const int qb = blockIdx.y;     // 0..15
    const int t = threadIdx.x, lane = t & 63, wave = t >> 6;
    const int half = wave >> 2, wv = wave & 3;
    const int quad2 = lane >> 5, l31 = lane & 31;
    const int th = t & 255;

    __shared__ __align__(16) char SM[66560];
    unsigned long long* mwS = (unsigned long long*)(SM + 66304);

    const float* mb = mask + (size_t)b * LL;
    #pragma unroll
    for (int i = 0; i < 4; ++i) {            // 8 waves x 4 = all 32 ballots
        const int tile = wave * 4 + i;
        const unsigned long long bal = __ballot(mb[tile * 64 + lane] > 0.5f);
        if (lane == 0) mwS[tile] = bal;
    }

    // stage Q (128 q x 64 d) to LDS [bk][row]: addr = c*16, c = bk*128+row
    const us* Qg = Qh + ((size_t)bh * LL + qb * 128) * DHH;
    #pragma unroll
    for (int i = 0; i < 2; ++i) {
        const int c = t + i * 512, row = c & 127, bk = c >> 7;
        *(bf16x8*)(SM + c * 16) = *(const bf16x8*)(Qg + row * DHH + bk * 8);
    }

    const us* Kbase = Kh + (size_t)bh * LL * DHH;
    const us* Vbase = Vh + ((size_t)b * CC + h * DHH) * LL;
    char* KH = SM + 16384 + half * 16640;    // this half's K double-buffer
    char* VH = SM + 49664 + half * 8320;     // this half's V buffer
    const int wrO = (th & 7) * 1040 + (th >> 3) * 16;  // staging write base
    const int rdO = quad2 * 1040 + l31 * 16;           // K/V fragment base
    const int qrd = quad2 * 2048 + (wv * 32 + l31) * 16; // Q fragment base
    const int g0 = half * 16;                // first tile of this half

    // stage tile g0: K into buffer 0, V
    #pragma unroll
    for (int i = 0; i < 2; ++i) {
        const int r = i * 32 + (th >> 3), bk = th & 7;
        *(bf16x8*)(KH + wrO + i * 512) =
            *(const bf16x8*)(Kbase + (size_t)(g0 * 64 + r) * DHH + bk * 8);
        *(bf16x8*)(VH + wrO + i * 512) =
            *(const bf16x8*)(Vbase + (size_t)r * LL + g0 * 64 + bk * 8);
    }
    __syncthreads();

    f32x16 of[2];
    #pragma unroll
    for (int mt = 0; mt < 2; ++mt)
        #pragma unroll
        for (int e = 0; e < 16; ++e) of[mt][e] = 0.f;
    float l_run = 0.f;

    for (int itl = 0; itl < 16; ++itl) {
        const int cur = itl & 1;
        char* Kc = KH + cur * 8320;          // K buffer holding tile itl
        char* Ka = KH + (1 - cur) * 8320;    // K buffer for tile itl+1

        // prefetch next K/V tile into registers (issue early)
        bf16x8 kpre[2], vpre[2];
        if (itl + 1 < 16) {
            const int n1 = (g0 + itl + 1) * 64;
            #pragma unroll
            for (int i = 0; i < 2; ++i) {
                const int r = i * 32 + (th >> 3), bk = th & 7;
                kpre[i] = *(const bf16x8*)(Kbase + (size_t)(n1 + r) * DHH + bk * 8);
                vpre[i] = *(const bf16x8*)(Vbase + (size_t)r * LL + n1 + bk * 8);
            }
        }

        // S^T = K^T Q (Q fragments re-read from LDS, affine)
        f32x16 sf[2];
        #pragma unroll
        for (int mt = 0; mt < 2; ++mt)
            #pragma unroll
            for (int e = 0; e < 16; ++e) sf[mt][e] = 0.f;
        __builtin_amdgcn_s_setprio(1);
        #pragma unroll
        for (int ks = 0; ks < 4; ++ks) {
            const bf16x8 qk = *(const bf16x8*)(SM + qrd + ks * 4096);
            #pragma unroll
            for (int mt = 0; mt < 2; ++mt) {
                const bf16x8 af = *(const bf16x8*)(Kc + rdO + ks * 2080 + mt * 512);
                sf[mt] = __builtin_amdgcn_mfma_f32_32x32x16_bf16(af, qk, sf[mt], 0, 0, 0);
            }
        }
        __builtin_amdgcn_s_setprio(0);

        // exp2-direct softmax weights (scores tiny in log2 units)
        const unsigned long long mw = mwS[g0 + itl];
        const bool masked = (mw != 0xFFFFFFFFFFFFFFFFull);
        float ps = 0.f;
        bf16x8 pfrag[4];
        #pragma unroll
        for (int mt = 0; mt < 2; ++mt) {
            float p[16];
            #pragma unroll
            for (int e = 0; e < 16; ++e) p[e] = EXP2(sf[mt][e]);
            if (masked) {
                #pragma unroll
                for (int e = 0; e < 16; ++e) {
                    const int row = 32 * mt + (e & 3) + 8 * (e >> 2) + 4 * quad2;
                    p[e] = ((mw >> row) & 1ull) ? p[e] : 0.f;
                }
            }
            const float s0 = (p[0] + p[1]) + (p[2] + p[3]);
            const float s1 = (p[4] + p[5]) + (p[6] + p[7]);
            const float s2 = (p[8] + p[9]) + (p[10] + p[11]);
            const float s3 = (p[12] + p[13]) + (p[14] + p[15]);
            ps += (s0 + s1) + (s2 + s3);
            // v_permlane32_swap_b32 vdst, vsrc:
            //   new_vdst = {lo: old_vdst.lo, hi: old_vsrc.lo}
            //   new_vsrc = {lo: old_vdst.hi, hi: old_vsrc.hi}
            // => vdst = low-n pair word (w0/w1), vsrc = +4 pair word (w2/w3).
            #pragma unroll
            for (int g = 0; g < 2; ++g) {
                unsigned w0 = pk2(p[8 * g + 0], p[8 * g + 1]);
                unsigned w1 = pk2(p[8 * g + 2], p[8 * g + 3]);
                unsigned w2 = pk2(p[8 * g + 4], p[8 * g + 5]);
                unsigned w3 = pk2(p[8 * g + 6], p[8 * g + 7]);
                asm("v_permlane32_swap_b32 %0, %1" : "+v"(w0), "+v"(w2));
                asm("v_permlane32_swap_b32 %0, %1" : "+v"(w1), "+v"(w3));
                uint4v u; u[0] = w0; u[1] = w1; u[2] = w2; u[3] = w3;
                pfrag[2 * mt + g] = __builtin_bit_cast(bf16x8, u);
            }
        }
        ps += __shfl_xor(ps, 32, 64);
        l_run += ps;

        // O^T += V P^T
        __builtin_amdgcn_s_setprio(1);
        #pragma unroll
        for (int ks = 0; ks < 4; ++ks)
            #pragma unroll
            for (int mt = 0; mt < 2; ++mt) {
                const bf16x8 vf = *(const bf16x8*)(VH + rdO + ks * 2080 + mt * 512);
                of[mt] = __builtin_amdgcn_mfma_f32_32x32x16_bf16(vf, pfrag[ks], of[mt], 0, 0, 0);
            }
        __builtin_amdgcn_s_setprio(0);

        // K-next into the alternate K buffer (free since last iteration)
        if (itl + 1 < 16) {
            #pragma unroll
            for (int i = 0; i < 2; ++i)
                *(bf16x8*)(Ka + wrO + i * 512) = kpre[i];
        }
        __syncthreads();                     // all PV reads of V done
        if (itl + 1 < 16) {
            #pragma unroll
            for (int i = 0; i < 2; ++i)
                *(bf16x8*)(VH + wrO + i * 512) = vpre[i];
        }
        __syncthreads();                     // V-next visible for next PV
    }

    // epilogue: merge halves (O = O0+O1, l = l0+l1), then ctx = O/l.
    // half1 parks partials in LDS (reuses Q/K region, dead now); half0
    // combines and writes. [chunk][lane] float4 layout -> conflict-free.
    float4* OS = (float4*)SM;                // 4 wv x 8 chunks x 64 lanes = 32KB
    float*  LS = (float*)(SM + 32768);       // 4 wv x 64 lanes
    const int qg = qb * 128 + wv * 32;
    if (half == 1) {
        #pragma unroll
        for (int mt = 0; mt < 2; ++mt)
            #pragma unroll
            for (int r4 = 0; r4 < 4; ++r4) {
                float4 v;
                v.x = of[mt][r4 * 4 + 0]; v.y = of[mt][r4 * 4 + 1];
                v.z = of[mt][r4 * 4 + 2]; v.w = of[mt][r4 * 4 + 3];
                OS[(wv * 8 + mt * 4 + r4) * 64 + lane] = v;
            }
        LS[wv * 64 + lane] = l_run;
    }
    __syncthreads();
    if (half == 0) {
        l_run += LS[wv * 64 + lane];
        const float inv = 1.0f / l_run;
        us* Cb = ctx + (size_t)b * LL * CC;
        const int q = qg + l31;
        #pragma unroll
        for (int mt = 0; mt < 2; ++mt)
            #pragma unroll
            for (int r4 = 0; r4 < 4; ++r4) {
                const float4 v = OS[(wv * 8 + mt * 4 + r4) * 64 + lane];
                const int d = 32 * mt + 8 * r4 + 4 * quad2;
                *(bf16x4*)(Cb + (size_t)q * CC + h * DHH + d) =
                    pk4((of[mt][r4 * 4 + 0] + v.x) * inv,
                        (of[mt][r4 * 4 + 1] + v.y) * inv,
                        (of[mt][r4 * 4 + 2] + v.z) * inv,
                        (of[mt][r4 * 4 + 3] + v.w) * inv);
            }
    }
}

// ---------------------------------------------------------------------------
extern "C" void kernel_launch(void* const* d_in, const int* in_sizes, int n_in,
                              void* d_out, int out_size, void* d_ws, size_t ws_size,
                              hipStream_t stream)
{
    const float* q    = (const float*)d_in[0];
    const float* k    = (const float*)d_in[1];
    const float* v    = (const float*)d_in[2];
    const float* mask = (const float*)d_in[3];
    const float* Wq   = (const float*)d_in[4];
    const float* bq   = (const float*)d_in[5];
    const float* Wk   = (const float*)d_in[6];
    const float* bk   = (const float*)d_in[7];
    const float* Wv   = (const float*)d_in[8];
    const float* bv   = (const float*)d_in[9];
    const float* Wout = (const float*)d_in[10];
    const float* bout = (const float*)d_in[11];

    const size_t TSZ  = (size_t)BB * CC * LL;    // 4,194,304 elements (8 MB)
    const size_t WSZ  = (size_t)4 * CC * CC;     // 1,048,576 elements (2 MB)
    const float SCALE_Q = 0.125f * 1.4426950408889634f;  // softmax scale * log2e

    const dim3 tb(256), gb(256);

    if (ws_size >= (6 * TSZ + WSZ) * sizeof(us)) {
        // fused path: 5 launches
        us* X0  = (us*)d_ws;
        us* X1  = X0 + TSZ;
        us* X2  = X1 + TSZ;
        us* qh  = X2 + TSZ;
        us* kh  = qh + TSZ;
        us* vh  = kh + TSZ;
        us* Wb  = vh + TSZ;
        us* ctx = X0;                            // X0 dead after proj3

        cvt_w4<<<dim3(CC * CC / 2048, 4), tb, 0, stream>>>(Wq, Wk, Wv, Wout, Wb);
        transpose_cvt3<<<dim3(LL / 64, CC / 64, 12), tb, 0, stream>>>(q, k, v, X0, X1, X2);
        proj_gemm3<<<dim3(LL / 128, CC / 128, 12), gb, 0, stream>>>(
            X0, X1, X2, Wb, bq, bk, bv, SCALE_Q, qh, kh, vh);
        attn_fwd<<<dim3(HH * BB, LL / 128), dim3(512), 0, stream>>>(qh, kh, vh, mask, ctx);
        proj_gemm<2><<<dim3(LL / 128, CC / 128, BB), gb, 0, stream>>>(
            ctx, Wb + 3 * (size_t)CC * CC, bout, 1.0f, d_out);
    } else {
        // fallback: sequential path reusing one Xt buffer
        us* Xt  = (us*)d_ws;
        us* qh  = Xt + TSZ;
        us* kh  = qh + TSZ;
        us* vh  = kh + TSZ;
        us* Wb  = vh + TSZ;
        us* ctx = Xt;

        const dim3 tg(LL / 64, CC / 64, BB), gg(LL / 128, CC / 128, BB);

        cvt_w4<<<dim3(CC * CC / 2048, 4), tb, 0, stream>>>(Wq, Wk, Wv, Wout, Wb);
        transpose_cvt<<<tg, tb, 0, stream>>>(q, Xt);
        proj_gemm<0><<<gg, gb, 0, stream>>>(Xt, Wb + 0 * (size_t)CC * CC, bq, SCALE_Q, (void*)qh);
        transpose_cvt<<<tg, tb, 0, stream>>>(k, Xt);
        proj_gemm<0><<<gg, gb, 0, stream>>>(Xt, Wb + 1 * (size_t)CC * CC, bk, 1.0f, (void*)kh);
        transpose_cvt<<<tg, tb, 0, stream>>>(v, Xt);
        proj_gemm<1><<<gg, gb, 0, stream>>>(Xt, Wb + 2 * (size_t)CC * CC, bv, 1.0f, (void*)vh);
        attn_fwd<<<dim3(HH * BB, LL / 128), dim3(512), 0, stream>>>(qh, kh, vh, mask, ctx);
        proj_gemm<2><<<gg, gb, 0, stream>>>(ctx, Wb + 3 * (size_t)CC * CC, bout, 1.0f, d_out);
    }
}